// Round 2
// baseline (143.582 us; speedup 1.0000x reference)
//
#include <hip/hip_runtime.h>
#include <hip/hip_bf16.h>

#define NATOMS 2048
#define K 48
#define P (NATOMS * K)
#define NR 5
#define NM 12
#define ND 17
#define HID 64

#define PI_F 3.14159265358979f
#define CUT 3.0f
#define RMIN_F 3.5f
#define AFC (-6.28318530717959f)   /* pi/(CUT-RMIN) = pi/(-0.5) */
#define POC (PI_F / CUT)           /* pi/3 */
#define SQ 0.816496580927726f      /* sqrt(2/3) */
#define E1C 1.45454545454545f      /* 16/11 */
#define CMC (-0.132231404958678f)  /* -16/121 */
/* exp2-folded constants (x * log2(e)) */
#define N4L (-5.77078016355585f)   /* -4 * log2e */
#define E1L (2.09846551402031f)    /* (16/11) * log2e */
#define TL2 (2.88539008177793f)    /* 2 * log2e */

// Packed bf16 weight layouts (built once per launch by k_prep).
__device__ unsigned short g_w1t[64 * 32];  // [n=h][k=j]  (k>=17 zero)
__device__ unsigned short g_w2t[64 * 64];  // [n=h2][k=h1]
__device__ unsigned short g_w2r[64 * 64];  // [n=h1][k=h2]
__device__ unsigned short g_w1r[32 * 64];  // [n=j][k=h]  (n>=17 zero)

using frag_ab = __attribute__((ext_vector_type(8))) short;
using frag_cd = __attribute__((ext_vector_type(4))) float;
using f2 = __attribute__((ext_vector_type(2))) float;
using f4 = __attribute__((ext_vector_type(4))) float;

__device__ __forceinline__ float fast_tanh(float x) {
    const float t = __builtin_amdgcn_exp2f(TL2 * x);
    return 1.0f - 2.0f * __builtin_amdgcn_rcpf(t + 1.0f);
}

__device__ __forceinline__ unsigned short f2bs(float x) {
    __hip_bfloat16 b = __float2bfloat16(x);
    return __builtin_bit_cast(unsigned short, b);
}

// LDS float atomic add (ds_add_f32, no-return form)
__device__ __forceinline__ void lds_add(float* p, float v) {
    __hip_atomic_fetch_add(p, v, __ATOMIC_RELAXED, __HIP_MEMORY_SCOPE_WORKGROUP);
}

// ---------------- Kernel 0: pack weights into MFMA-ready bf16 layouts -----
__global__ __launch_bounds__(256) void k_prep(const float* __restrict__ W1,
                                              const float* __restrict__ W2) {
    const int i = blockIdx.x * 256 + threadIdx.x;  // grid covers 12288
    if (i < 2048) {                                   // W1T[n][k]
        const int n = i >> 5, k = i & 31;
        g_w1t[i] = (k < ND) ? f2bs(W1[k * HID + n]) : (unsigned short)0;
    } else if (i < 2048 + 4096) {                     // W2T[n][k]
        const int j = i - 2048, n = j >> 6, k = j & 63;
        g_w2t[j] = f2bs(W2[k * HID + n]);
    } else if (i < 2048 + 8192) {                     // W2R[n][k]
        const int j = i - (2048 + 4096);
        g_w2r[j] = f2bs(W2[j]);
    } else if (i < 2048 + 8192 + 2048) {              // W1R[n][k]
        const int j = i - (2048 + 8192), n = j >> 6;
        g_w1r[j] = (n < ND) ? f2bs(W1[j]) : (unsigned short)0;
    }
}

// ---------------- Fused kernel: block = 1 atom (48 pairs), 4 waves --------
// Region liveness packing (max-live 23,040 B = 45*512 -> up to 7 blocks/CU):
//  R1 @0     (9408): g3sum[48*13]f32 (ph0-3) | gz2S[48*72]s16 (ph5-6) | S[48*49]f32 (8b-8c)
//  R2 @9408  (3840): descS[48*40]s16 (ph0-4) | sgd[48*19]f32 (ph7-8d)
//  H1 @13248 (6912): h1S[48*72]s16 (ph4-7)
//  SE @20160 (768), SU @20928 (768), SFC @21696, SFK @21888,
//  SGF @22080 (192), SGU @22272 (768)   (sgf+sgu contiguous for zeroing)
#define R2_OFF   9408
#define H1_OFF   13248
#define SE_OFF   20160
#define SU_OFF   20928
#define SFC_OFF  21696
#define SFK_OFF  21888
#define SGF_OFF  22080
#define SGU_OFF  22272
#define SM_BYTES 23040

__global__ __launch_bounds__(256, 6) void k_fused(const float* __restrict__ rij,
                                                  const float* __restrict__ b1,
                                                  const float* __restrict__ b2,
                                                  const float* __restrict__ W3,
                                                  const float* __restrict__ b3,
                                                  float* __restrict__ out) {
    __shared__ __align__(16) char smem[SM_BYTES];
    float* g3sum = (float*)(smem);              // [k*13+m]
    short* gz2S  = (short*)(smem);              // [row*72+n]
    float* sS    = (float*)(smem);              // [k*49+l]
    short* descS = (short*)(smem + R2_OFF);     // [row*40+j]
    float* sgd   = (float*)(smem + R2_OFF);     // [k*19+{0..16:gdesc,17:eij}]
    short* h1S   = (short*)(smem + H1_OFF);     // [row*72+n]
    float* se    = (float*)(smem + SE_OFF);     // [w*48+row]
    float* su    = (float*)(smem + SU_OFF);     // [4k+{x,y,z,d}]
    float* sfc   = (float*)(smem + SFC_OFF);
    float* sfk   = (float*)(smem + SFK_OFF);
    float* sgf   = (float*)(smem + SGF_OFF);    // [l]
    float* sgu   = (float*)(smem + SGU_OFF);    // [4k+c]

    const int t = threadIdx.x;
    const int base3 = blockIdx.x * (K * 3);

    // ---- phase 0: zero accumulators; per-pair geometry ----
    if (t < 156) {                                    // g3sum (2496 B)
        *(f4*)(smem + 16 * t) = (f4){0.0f, 0.0f, 0.0f, 0.0f};
    } else if (t < 216) {                             // sgf+sgu (960 B)
        *(f4*)(smem + SGF_OFF + 16 * (t - 156)) = (f4){0.0f, 0.0f, 0.0f, 0.0f};
    }
    if (t < K) {
        const float x = rij[base3 + 3 * t];
        const float y = rij[base3 + 3 * t + 1];
        const float z = rij[base3 + 3 * t + 2];
        float s2 = fmaxf(x * x + y * y + z * z, 1e-24f);
        const float inv = __builtin_amdgcn_rsqf(s2);
        const float d = s2 * inv;
        *(f4*)&su[4 * t] = (f4){x * inv, y * inv, z * inv, d};
        sfk[t] = 0.5f + 0.5f * __cosf(POC * d);
        sfc[t] = (d > RMIN_F) ? (0.5f + 0.5f * __cosf(AFC * (d - RMIN_F))) : 1.0f;
#pragma unroll
        for (int c = ND; c < 32; c++) descS[t * 40 + c] = 0;  // K-pad
    }
    __syncthreads();

    // ---- phase 1: cosang partials -> g3sum atomics; rbf ----
    if (t < 192) {
        const int ch = t / 48, k = t - ch * 48;
        const f4 uk = *(const f4*)&su[4 * k];
        const float* sul = &su[4 * (ch * 12)];
        f2 partv[6];
#pragma unroll
        for (int i = 0; i < 6; i++) partv[i] = (f2){0.0f, 0.0f};
#pragma unroll
        for (int li = 0; li < 12; li++) {
            const int l = ch * 12 + li;
            const f4 ul = *(const f4*)&sul[4 * li];
            float c = uk.x * ul.x + uk.y * ul.y + uk.z * ul.z;
            if (k == l) c = 0.0f;
            const float cp1 = c + 1.0f;
            const float e0 = __builtin_amdgcn_exp2f(N4L * cp1 * cp1) * sfk[l];
            const float e1 = __builtin_amdgcn_exp2f(E1L * cp1);
            const float e2s = e1 * e1;
            const f2 e2v = {e2s, e2s};
            f2 tm = {e0, e0 * e1};
            partv[0] += tm;
#pragma unroll
            for (int i = 1; i < 6; i++) { tm *= e2v; partv[i] += tm; }
        }
        float* gp = &g3sum[k * 13];
#pragma unroll
        for (int i = 0; i < 6; i++) {
            lds_add(&gp[2 * i], partv[i].x);
            lds_add(&gp[2 * i + 1], partv[i].y);
        }
    } else {
#pragma unroll
        for (int r = 0; r < 4; r++) {
            const int idx = (t - 192) + 64 * r;     // 240 = 48 pairs x 5 rbf
            if (idx < K * NR) {
                const int p = idx / NR, n = idx - NR * p;
                const float d = su[4 * p + 3];
                const float s = SQ * sfc[p] * __builtin_amdgcn_rcpf(d);
                descS[p * 40 + n] = (short)f2bs(s * __sinf((float)(n + 1) * POC * d));
            }
        }
    }
    __syncthreads();

    // ---- phase 3: convert g3sum -> desc cols 5..16 (C_m recomputed) ----
    if (t < 192) {
        const int k = t >> 2, q = t & 3;   // 3 m's per thread
#pragma unroll
        for (int i = 0; i < 3; i++) {
            const int m = q * 3 + i;
            const float cm = __expf(CMC * (float)(m * m));
            descS[k * 40 + NR + m] = (short)f2bs(g3sum[k * 13 + m] * cm);
        }
    }
    __syncthreads();

    const int w = t >> 6, lane = t & 63, quad = lane >> 4, lm = lane & 15;
    const int n0 = w * 16 + lm;

    // ---- phase 4 (fwd1): h1 = tanh(desc @ W1 + b1); t1 in registers ----
    float t1[3][4];
    {
        const frag_ab bf = *(const frag_ab*)&g_w1t[n0 * 32 + quad * 8];
        const float bias = b1[n0];
#pragma unroll
        for (int mt = 0; mt < 3; mt++) {
            const frag_ab a = *(const frag_ab*)&descS[(mt * 16 + lm) * 40 + quad * 8];
            frag_cd acc = {bias, bias, bias, bias};
            acc = __builtin_amdgcn_mfma_f32_16x16x32_bf16(a, bf, acc, 0, 0, 0);
#pragma unroll
            for (int r = 0; r < 4; r++) {
                const float tv = fast_tanh(acc[r]);
                t1[mt][r] = tv;
                h1S[(mt * 16 + quad * 4 + r) * 72 + n0] = (short)f2bs(tv);
            }
        }
    }
    __syncthreads();

    // ---- phase 5 (fwd2): t2 = tanh(h1@W2+b2); e partials; gz2 ----
    {
        const frag_ab b0 = *(const frag_ab*)&g_w2t[n0 * 64 + quad * 8];
        const frag_ab b1f = *(const frag_ab*)&g_w2t[n0 * 64 + 32 + quad * 8];
        const float bias = b2[n0];
        const float w3n = W3[n0];
#pragma unroll
        for (int mt = 0; mt < 3; mt++) {
            const frag_ab a0 = *(const frag_ab*)&h1S[(mt * 16 + lm) * 72 + quad * 8];
            const frag_ab a1 = *(const frag_ab*)&h1S[(mt * 16 + lm) * 72 + 32 + quad * 8];
            frag_cd acc = {bias, bias, bias, bias};
            acc = __builtin_amdgcn_mfma_f32_16x16x32_bf16(a0, b0, acc, 0, 0, 0);
            acc = __builtin_amdgcn_mfma_f32_16x16x32_bf16(a1, b1f, acc, 0, 0, 0);
            float ep[4];
#pragma unroll
            for (int r = 0; r < 4; r++) {
                const int row = mt * 16 + quad * 4 + r;
                const float tv = fast_tanh(acc[r]);
                ep[r] = tv * w3n;
                gz2S[row * 72 + n0] = (short)f2bs(sfc[row] * w3n * (1.0f - tv * tv));
            }
#pragma unroll
            for (int off = 1; off < 16; off <<= 1) {
#pragma unroll
                for (int r = 0; r < 4; r++) ep[r] += __shfl_xor(ep[r], off, 64);
            }
            if (lm == 0) {
#pragma unroll
                for (int r = 0; r < 4; r++) se[w * 48 + mt * 16 + quad * 4 + r] = ep[r];
            }
        }
    }
    __syncthreads();

    // ---- phase 6 (bwd1): gz1 = (gz2 @ W2^T)*(1-t1^2) -> overwrite h1S ----
    {
        const frag_ab b0 = *(const frag_ab*)&g_w2r[n0 * 64 + quad * 8];
        const frag_ab b1f = *(const frag_ab*)&g_w2r[n0 * 64 + 32 + quad * 8];
#pragma unroll
        for (int mt = 0; mt < 3; mt++) {
            const frag_ab a0 = *(const frag_ab*)&gz2S[(mt * 16 + lm) * 72 + quad * 8];
            const frag_ab a1 = *(const frag_ab*)&gz2S[(mt * 16 + lm) * 72 + 32 + quad * 8];
            frag_cd acc = {0.0f, 0.0f, 0.0f, 0.0f};
            acc = __builtin_amdgcn_mfma_f32_16x16x32_bf16(a0, b0, acc, 0, 0, 0);
            acc = __builtin_amdgcn_mfma_f32_16x16x32_bf16(a1, b1f, acc, 0, 0, 0);
#pragma unroll
            for (int r = 0; r < 4; r++) {
                const float g = acc[r] * (1.0f - t1[mt][r] * t1[mt][r]);
                h1S[(mt * 16 + quad * 4 + r) * 72 + n0] = (short)f2bs(g);
            }
        }
    }
    __syncthreads();

    // ---- phase 7 (bwd2): gdesc = gz1 @ W1^T -> sgd (pre-scaled by C_m) ----
    for (int tid = w; tid < 6; tid += 4) {
        const int mt = tid >> 1, nt = tid & 1, n = nt * 16 + lm;
        const frag_ab b0 = *(const frag_ab*)&g_w1r[n * 64 + quad * 8];
        const frag_ab b1f = *(const frag_ab*)&g_w1r[n * 64 + 32 + quad * 8];
        const frag_ab a0 = *(const frag_ab*)&h1S[(mt * 16 + lm) * 72 + quad * 8];
        const frag_ab a1 = *(const frag_ab*)&h1S[(mt * 16 + lm) * 72 + 32 + quad * 8];
        frag_cd acc = {0.0f, 0.0f, 0.0f, 0.0f};
        acc = __builtin_amdgcn_mfma_f32_16x16x32_bf16(a0, b0, acc, 0, 0, 0);
        acc = __builtin_amdgcn_mfma_f32_16x16x32_bf16(a1, b1f, acc, 0, 0, 0);
        if (n < ND) {
            const int mm = n - NR;
            const float cmul = (n >= NR) ? __expf(CMC * (float)(mm * mm)) : 1.0f;
#pragma unroll
            for (int r = 0; r < 4; r++)
                sgd[(mt * 16 + quad * 4 + r) * 19 + n] = acc[r] * cmul;
        }
    }
    if (t < K)
        sgd[t * 19 + 17] = se[t] + se[48 + t] + se[96 + t] + se[144 + t] + b3[0];
    __syncthreads();

    // ---- phase 8b: dual Horner; S -> LDS; sgf/sgu term1 via atomics ----
    // k-rotation spreads the sgf[l] atomic across 12 addresses (4-way max).
    if (t < 192) {
        const int ch = t / 48, k = t - ch * 48;
        f2 gm[NM];
#pragma unroll
        for (int m = 0; m < NM; m++) {
            const float g = sgd[k * 19 + NR + m];
            gm[m] = (f2){g, (float)m * g};
        }
        const f4 uk = *(const f4*)&su[4 * k];
        int r = k % 12;
        float gkx = 0.0f, gky = 0.0f, gkz = 0.0f;
#pragma unroll
        for (int li = 0; li < 12; li++) {
            const int l = ch * 12 + r;
            r = (r == 11) ? 0 : r + 1;
            const f4 ul = *(const f4*)&su[4 * l];
            float c = uk.x * ul.x + uk.y * ul.y + uk.z * ul.z;
            if (k == l) c = 0.0f;
            const float cp1 = c + 1.0f;
            const float e0 = __builtin_amdgcn_exp2f(N4L * cp1 * cp1);
            const float x = __builtin_amdgcn_exp2f(E1L * cp1);
            const f2 xx = {x, x};
            f2 pd = gm[11];
#pragma unroll
            for (int m = 10; m >= 1; m--) pd = __builtin_elementwise_fma(pd, xx, gm[m]);
            const float Pv = fmaf(pd.x, x, gm[0].x);
            const float T = e0 * Pv;
            const float U = e0 * x * pd.y;
            const float Sp = fmaf(cp1, T, -(2.0f / 11.0f) * U);
            const float Sv = (k == l) ? 0.0f : (-8.0f) * Sp;
            sS[k * 49 + l] = Sv;
            lds_add(&sgf[l], T);
            const float A = Sv * sfk[l];
            gkx = fmaf(A, ul.x, gkx);
            gky = fmaf(A, ul.y, gky);
            gkz = fmaf(A, ul.z, gkz);
        }
        lds_add(&sgu[4 * k + 0], gkx);
        lds_add(&sgu[4 * k + 1], gky);
        lds_add(&sgu[4 * k + 2], gkz);
    }
    __syncthreads();

    // ---- phase 8c: sgu term2 = fk[k] * sum_l S[l][k]*u[l] (4-wave partial) ----
    if (lane < K) {
        const int k = lane;
        float t2x = 0.0f, t2y = 0.0f, t2z = 0.0f;
#pragma unroll
        for (int l = 12 * w; l < 12 * w + 12; l++) {
            const float Sv = sS[l * 49 + k];
            const f4 ul = *(const f4*)&su[4 * l];
            t2x = fmaf(Sv, ul.x, t2x);
            t2y = fmaf(Sv, ul.y, t2y);
            t2z = fmaf(Sv, ul.z, t2z);
        }
        const float fk = sfk[k];
        lds_add(&sgu[4 * k + 0], fk * t2x);
        lds_add(&sgu[4 * k + 1], fk * t2y);
        lds_add(&sgu[4 * k + 2], fk * t2z);
    }
    __syncthreads();

    // ---- phase 8d: assemble gradient, write out ----
    if (t < K) {
        const float sgf_t = sgf[t];
        const float gux = sgu[4 * t + 0];
        const float guy = sgu[4 * t + 1];
        const float guz = sgu[4 * t + 2];
        const f4 uv = *(const f4*)&su[4 * t];
        const float d = uv.w;
        const float ux = uv.x, uy = uv.y, uz = uv.z;
        const float invd = __builtin_amdgcn_rcpf(d);
        float gfc = sgd[t * 19 + 17];
        float gdR = 0.0f;
#pragma unroll
        for (int n = 0; n < NR; n++) {
            const float bn = (float)(n + 1) * POC;
            float sn, cn;
            __sincosf(bn * d, &sn, &cn);
            const float g = sgd[t * 19 + n];
            gfc = fmaf(g, SQ * sn * invd, gfc);
            gdR = fmaf(g, SQ * (bn * cn - sn * invd) * invd, gdR);
        }
        const float fc = sfc[t];
        float dfc = 0.0f;
        if (d > RMIN_F) dfc = -0.5f * AFC * __sinf(AFC * (d - RMIN_F));
        const float dfcrik = -0.5f * POC * __sinf(POC * d);

        const float gd = fc * gdR + gfc * dfc + sgf_t * dfcrik;
        const float dot = gux * ux + guy * uy + guz * uz;

        out[base3 + 3 * t + 0] = fmaf(gd, ux, (gux - dot * ux) * invd);
        out[base3 + 3 * t + 1] = fmaf(gd, uy, (guy - dot * uy) * invd);
        out[base3 + 3 * t + 2] = fmaf(gd, uz, (guz - dot * uz) * invd);
    }
}

extern "C" void kernel_launch(void* const* d_in, const int* in_sizes, int n_in,
                              void* d_out, int out_size, void* d_ws, size_t ws_size,
                              hipStream_t stream) {
    (void)in_sizes; (void)n_in; (void)out_size; (void)d_ws; (void)ws_size;
    const float* rij = (const float*)d_in[0];
    // d_in[1] = unique_i (unused: dense K neighbors per atom)
    const float* W1 = (const float*)d_in[2];
    const float* b1 = (const float*)d_in[3];
    const float* W2 = (const float*)d_in[4];
    const float* b2 = (const float*)d_in[5];
    const float* W3 = (const float*)d_in[6];
    const float* b3 = (const float*)d_in[7];
    float* out = (float*)d_out;

    k_prep<<<48, 256, 0, stream>>>(W1, W2);
    k_fused<<<NATOMS, 256, 0, stream>>>(rij, b1, b2, W3, b3, out);
}

// Round 3
// 92.631 us; speedup vs baseline: 1.5501x; 1.5501x over previous
//
#include <hip/hip_runtime.h>
#include <hip/hip_bf16.h>

#define NATOMS 2048
#define K 48
#define P (NATOMS * K)
#define NR 5
#define NM 12
#define ND 17
#define HID 64

#define PI_F 3.14159265358979f
#define CUT 3.0f
#define RMIN_F 3.5f
#define AFC (-6.28318530717959f)   /* pi/(CUT-RMIN) = pi/(-0.5) */
#define POC (PI_F / CUT)           /* pi/3 */
#define SQ 0.816496580927726f      /* sqrt(2/3) */
#define E1C 1.45454545454545f      /* 16/11 */
#define CMC (-0.132231404958678f)  /* -16/121 */
/* exp2-folded constants (x * log2(e)) */
#define N4L (-5.77078016355585f)   /* -4 * log2e */
#define E1L (2.09846551402031f)    /* (16/11) * log2e */
#define TL2 (2.88539008177793f)    /* 2 * log2e */

// Packed bf16 weight layouts (built once per launch by k_prep).
__device__ unsigned short g_w1t[64 * 32];  // [n=h][k=j]  (k>=17 zero)
__device__ unsigned short g_w2t[64 * 64];  // [n=h2][k=h1]
__device__ unsigned short g_w2r[64 * 64];  // [n=h1][k=h2]
__device__ unsigned short g_w1r[32 * 64];  // [n=j][k=h]  (n>=17 zero)

using frag_ab = __attribute__((ext_vector_type(8))) short;
using frag_cd = __attribute__((ext_vector_type(4))) float;
using f2 = __attribute__((ext_vector_type(2))) float;
using f4 = __attribute__((ext_vector_type(4))) float;

__device__ __forceinline__ float fast_tanh(float x) {
    const float t = __builtin_amdgcn_exp2f(TL2 * x);
    return 1.0f - 2.0f * __builtin_amdgcn_rcpf(t + 1.0f);
}

__device__ __forceinline__ unsigned short f2bs(float x) {
    __hip_bfloat16 b = __float2bfloat16(x);
    return __builtin_bit_cast(unsigned short, b);
}

__device__ __forceinline__ float bs2f(unsigned short u) {
    return __builtin_bit_cast(float, ((unsigned)u) << 16);
}

// ---------------- Kernel 0: pack weights into MFMA-ready bf16 layouts -----
__global__ __launch_bounds__(256) void k_prep(const float* __restrict__ W1,
                                              const float* __restrict__ W2) {
    const int i = blockIdx.x * 256 + threadIdx.x;  // grid covers 12288
    if (i < 2048) {                                   // W1T[n][k]
        const int n = i >> 5, k = i & 31;
        g_w1t[i] = (k < ND) ? f2bs(W1[k * HID + n]) : (unsigned short)0;
    } else if (i < 2048 + 4096) {                     // W2T[n][k]
        const int j = i - 2048, n = j >> 6, k = j & 63;
        g_w2t[j] = f2bs(W2[k * HID + n]);
    } else if (i < 2048 + 8192) {                     // W2R[n][k]
        const int j = i - (2048 + 4096);
        g_w2r[j] = f2bs(W2[j]);
    } else if (i < 2048 + 8192 + 2048) {              // W1R[n][k]
        const int j = i - (2048 + 8192), n = j >> 6;
        g_w1r[j] = (n < ND) ? f2bs(W1[j]) : (unsigned short)0;
    }
}

// ---------------- Fused kernel: block = 1 atom (48 pairs), 4 waves --------
// LDS layout: 20,448 B -> 20,480 alloc -> 8 blocks/CU (grid = 8 blocks/CU).
//  A @0     (6912): h1S [48][72]s16 (ph4-7)   | sT bf16 [48][49] (8b-8c)
//  B @6912  (6912): descS [48][40]s16 (ph0-4) | gz2S [48][72]s16 (ph5-6)
//                   | sgd [48][19]f32 @6912 + sgf4 @10560 + sgu4 @11328 (7-8d)
//  C @13824 (4704): sS bf16 [48][49] (8b-8c)
//  SE @18528 (768), SU @19296 (768), SFC @20064 (192), SFK @20256 (192)
#define H1_OFF   0
#define ST_OFF   0
#define DESC_OFF 6912
#define GZ2_OFF  6912
#define SGD_OFF  6912
#define SGF_OFF  10560
#define SGU_OFF  11328
#define SS_OFF   13824
#define SE_OFF   18528
#define SU_OFF   19296
#define SFC_OFF  20064
#define SFK_OFF  20256
#define SM_BYTES 20448

__global__ __launch_bounds__(256, 8) void k_fused(const float* __restrict__ rij,
                                                  const float* __restrict__ b1,
                                                  const float* __restrict__ b2,
                                                  const float* __restrict__ W3,
                                                  const float* __restrict__ b3,
                                                  float* __restrict__ out) {
    __shared__ __align__(16) char smem[SM_BYTES];
    short*          h1S   = (short*)(smem + H1_OFF);           // [row*72+n]
    unsigned short* sT    = (unsigned short*)(smem + ST_OFF);  // [k*49+l] bf16
    short*          descS = (short*)(smem + DESC_OFF);         // [row*40+j]
    short*          gz2S  = (short*)(smem + GZ2_OFF);          // [row*72+n]
    float*          sgd   = (float*)(smem + SGD_OFF);          // [k*19+{0..16,17:eij}]
    float*          sgf4  = (float*)(smem + SGF_OFF);          // [w*48+l]
    float*          sgu4  = (float*)(smem + SGU_OFF);          // [(w*48+k)*3+c]
    unsigned short* sS    = (unsigned short*)(smem + SS_OFF);  // [k*49+l] bf16
    float*          se    = (float*)(smem + SE_OFF);           // [w*48+row]
    float*          su    = (float*)(smem + SU_OFF);           // [4k+{x,y,z,d}]
    float*          sfc   = (float*)(smem + SFC_OFF);
    float*          sfk   = (float*)(smem + SFK_OFF);

    const int t = threadIdx.x;
    const int base3 = blockIdx.x * (K * 3);

    // ---- phase 0: per-pair geometry ----
    if (t < K) {
        const float x = rij[base3 + 3 * t];
        const float y = rij[base3 + 3 * t + 1];
        const float z = rij[base3 + 3 * t + 2];
        float s2 = fmaxf(x * x + y * y + z * z, 1e-24f);
        const float inv = __builtin_amdgcn_rsqf(s2);
        const float d = s2 * inv;
        *(f4*)&su[4 * t] = (f4){x * inv, y * inv, z * inv, d};
        sfk[t] = 0.5f + 0.5f * __cosf(POC * d);
        sfc[t] = (d > RMIN_F) ? (0.5f + 0.5f * __cosf(AFC * (d - RMIN_F))) : 1.0f;
#pragma unroll
        for (int c = ND; c < 32; c++) descS[t * 40 + c] = 0;  // K-pad
    }
    __syncthreads();

    // ---- phase 1: cosang + 3-body partials (shuffle-reduced); rbf ----
    // mapping t = 4k+ch: 4 chunk-partials of row k sit in adjacent lanes.
    if (t < 192) {
        const int k = t >> 2, ch = t & 3;
        const f4 uk = *(const f4*)&su[4 * k];
        const float* sul = &su[4 * (ch * 12)];
        f2 partv[6];
#pragma unroll
        for (int i = 0; i < 6; i++) partv[i] = (f2){0.0f, 0.0f};
#pragma unroll
        for (int li = 0; li < 12; li++) {
            const int l = ch * 12 + li;
            const f4 ul = *(const f4*)&sul[4 * li];
            float c = uk.x * ul.x + uk.y * ul.y + uk.z * ul.z;
            if (k == l) c = 0.0f;
            const float cp1 = c + 1.0f;
            const float e0 = __builtin_amdgcn_exp2f(N4L * cp1 * cp1) * sfk[l];
            const float e1 = __builtin_amdgcn_exp2f(E1L * cp1);
            const float e2s = e1 * e1;
            const f2 e2v = {e2s, e2s};
            f2 tm = {e0, e0 * e1};
            partv[0] += tm;
#pragma unroll
            for (int i = 1; i < 6; i++) { tm *= e2v; partv[i] += tm; }
        }
        // reduce across the 4 chunk lanes (xor 1, then xor 2)
#pragma unroll
        for (int i = 0; i < 6; i++) {
            partv[i].x += __shfl_xor(partv[i].x, 1);
            partv[i].y += __shfl_xor(partv[i].y, 1);
            partv[i].x += __shfl_xor(partv[i].x, 2);
            partv[i].y += __shfl_xor(partv[i].y, 2);
        }
        if (ch == 0) {
#pragma unroll
            for (int i = 0; i < 6; i++) {
                const int m0 = 2 * i, m1 = 2 * i + 1;
                descS[k * 40 + NR + m0] =
                    (short)f2bs(partv[i].x * __expf(CMC * (float)(m0 * m0)));
                descS[k * 40 + NR + m1] =
                    (short)f2bs(partv[i].y * __expf(CMC * (float)(m1 * m1)));
            }
        }
    } else {
#pragma unroll
        for (int r = 0; r < 4; r++) {
            const int idx = (t - 192) + 64 * r;     // 240 = 48 pairs x 5 rbf
            if (idx < K * NR) {
                const int p = idx / NR, n = idx - NR * p;
                const float d = su[4 * p + 3];
                const float s = SQ * sfc[p] * __builtin_amdgcn_rcpf(d);
                descS[p * 40 + n] = (short)f2bs(s * __sinf((float)(n + 1) * POC * d));
            }
        }
    }
    __syncthreads();

    const int w = t >> 6, lane = t & 63, quad = lane >> 4, lm = lane & 15;
    const int n0 = w * 16 + lm;

    // ---- phase 4 (fwd1): h1 = tanh(desc @ W1 + b1); t1 in registers ----
    float t1[3][4];
    {
        const frag_ab bf = *(const frag_ab*)&g_w1t[n0 * 32 + quad * 8];
        const float bias = b1[n0];
#pragma unroll
        for (int mt = 0; mt < 3; mt++) {
            const frag_ab a = *(const frag_ab*)&descS[(mt * 16 + lm) * 40 + quad * 8];
            frag_cd acc = {bias, bias, bias, bias};
            acc = __builtin_amdgcn_mfma_f32_16x16x32_bf16(a, bf, acc, 0, 0, 0);
#pragma unroll
            for (int r = 0; r < 4; r++) {
                const float tv = fast_tanh(acc[r]);
                t1[mt][r] = tv;
                h1S[(mt * 16 + quad * 4 + r) * 72 + n0] = (short)f2bs(tv);
            }
        }
    }
    __syncthreads();

    // ---- phase 5 (fwd2): t2 = tanh(h1@W2+b2); e partials; gz2 ----
    {
        const frag_ab b0 = *(const frag_ab*)&g_w2t[n0 * 64 + quad * 8];
        const frag_ab b1f = *(const frag_ab*)&g_w2t[n0 * 64 + 32 + quad * 8];
        const float bias = b2[n0];
        const float w3n = W3[n0];
#pragma unroll
        for (int mt = 0; mt < 3; mt++) {
            const frag_ab a0 = *(const frag_ab*)&h1S[(mt * 16 + lm) * 72 + quad * 8];
            const frag_ab a1 = *(const frag_ab*)&h1S[(mt * 16 + lm) * 72 + 32 + quad * 8];
            frag_cd acc = {bias, bias, bias, bias};
            acc = __builtin_amdgcn_mfma_f32_16x16x32_bf16(a0, b0, acc, 0, 0, 0);
            acc = __builtin_amdgcn_mfma_f32_16x16x32_bf16(a1, b1f, acc, 0, 0, 0);
            float ep[4];
#pragma unroll
            for (int r = 0; r < 4; r++) {
                const int row = mt * 16 + quad * 4 + r;
                const float tv = fast_tanh(acc[r]);
                ep[r] = tv * w3n;
                gz2S[row * 72 + n0] = (short)f2bs(sfc[row] * w3n * (1.0f - tv * tv));
            }
#pragma unroll
            for (int off = 1; off < 16; off <<= 1) {
#pragma unroll
                for (int r = 0; r < 4; r++) ep[r] += __shfl_xor(ep[r], off, 64);
            }
            if (lm == 0) {
#pragma unroll
                for (int r = 0; r < 4; r++) se[w * 48 + mt * 16 + quad * 4 + r] = ep[r];
            }
        }
    }
    __syncthreads();

    // ---- phase 6 (bwd1): gz1 = (gz2 @ W2^T)*(1-t1^2) -> overwrite h1S ----
    {
        const frag_ab b0 = *(const frag_ab*)&g_w2r[n0 * 64 + quad * 8];
        const frag_ab b1f = *(const frag_ab*)&g_w2r[n0 * 64 + 32 + quad * 8];
#pragma unroll
        for (int mt = 0; mt < 3; mt++) {
            const frag_ab a0 = *(const frag_ab*)&gz2S[(mt * 16 + lm) * 72 + quad * 8];
            const frag_ab a1 = *(const frag_ab*)&gz2S[(mt * 16 + lm) * 72 + 32 + quad * 8];
            frag_cd acc = {0.0f, 0.0f, 0.0f, 0.0f};
            acc = __builtin_amdgcn_mfma_f32_16x16x32_bf16(a0, b0, acc, 0, 0, 0);
            acc = __builtin_amdgcn_mfma_f32_16x16x32_bf16(a1, b1f, acc, 0, 0, 0);
#pragma unroll
            for (int r = 0; r < 4; r++) {
                const float g = acc[r] * (1.0f - t1[mt][r] * t1[mt][r]);
                h1S[(mt * 16 + quad * 4 + r) * 72 + n0] = (short)f2bs(g);
            }
        }
    }
    __syncthreads();

    // ---- phase 7 (bwd2): gdesc = gz1 @ W1^T -> sgd (pre-scaled by C_m) ----
    for (int tid = w; tid < 6; tid += 4) {
        const int mt = tid >> 1, nt = tid & 1, n = nt * 16 + lm;
        const frag_ab b0 = *(const frag_ab*)&g_w1r[n * 64 + quad * 8];
        const frag_ab b1f = *(const frag_ab*)&g_w1r[n * 64 + 32 + quad * 8];
        const frag_ab a0 = *(const frag_ab*)&h1S[(mt * 16 + lm) * 72 + quad * 8];
        const frag_ab a1 = *(const frag_ab*)&h1S[(mt * 16 + lm) * 72 + 32 + quad * 8];
        frag_cd acc = {0.0f, 0.0f, 0.0f, 0.0f};
        acc = __builtin_amdgcn_mfma_f32_16x16x32_bf16(a0, b0, acc, 0, 0, 0);
        acc = __builtin_amdgcn_mfma_f32_16x16x32_bf16(a1, b1f, acc, 0, 0, 0);
        if (n < ND) {
            const int mm = n - NR;
            const float cmul = (n >= NR) ? __expf(CMC * (float)(mm * mm)) : 1.0f;
#pragma unroll
            for (int r = 0; r < 4; r++)
                sgd[(mt * 16 + quad * 4 + r) * 19 + n] = acc[r] * cmul;
        }
    }
    if (t < K)
        sgd[t * 19 + 17] = se[t] + se[48 + t] + se[96 + t] + se[144 + t] + b3[0];
    __syncthreads();

    // ---- phase 8b: recompute cos; dual Horner; S,T -> LDS (bf16) ----
    // mapping t = 4k+ch (same as ph1): broadcast gm reads, spread writes.
    if (t < 192) {
        const int k = t >> 2, ch = t & 3;
        f2 gm[NM];
#pragma unroll
        for (int m = 0; m < NM; m++) {
            const float g = sgd[k * 19 + NR + m];
            gm[m] = (f2){g, (float)m * g};
        }
        const f4 uk = *(const f4*)&su[4 * k];
        const float* sul = &su[4 * (ch * 12)];
#pragma unroll
        for (int li = 0; li < 12; li++) {
            const int l = ch * 12 + li;
            const f4 ul = *(const f4*)&sul[4 * li];
            float c = uk.x * ul.x + uk.y * ul.y + uk.z * ul.z;
            if (k == l) c = 0.0f;
            const float cp1 = c + 1.0f;
            const float e0 = __builtin_amdgcn_exp2f(N4L * cp1 * cp1);
            const float x = __builtin_amdgcn_exp2f(E1L * cp1);
            const f2 xx = {x, x};
            f2 pd = gm[11];
#pragma unroll
            for (int m = 10; m >= 1; m--) pd = __builtin_elementwise_fma(pd, xx, gm[m]);
            const float Pv = fmaf(pd.x, x, gm[0].x);
            const float T = e0 * Pv;
            const float U = e0 * x * pd.y;
            const float Sp = fmaf(cp1, T, -(2.0f / 11.0f) * U);
            const float Sv = (k == l) ? 0.0f : (-8.0f) * Sp;
            sT[k * 49 + l] = f2bs(T);
            sS[k * 49 + l] = f2bs(Sv);
        }
    }
    __syncthreads();

    // ---- phase 8c: partial reductions, all 4 waves ----
    if (lane < K) {
        float s = 0.0f;
#pragma unroll
        for (int kk = 12 * w; kk < 12 * w + 12; kk++) s += bs2f(sT[kk * 49 + lane]);
        sgf4[w * 48 + lane] = s;

        const int k = lane;
        const float fk = sfk[k];
        float gx = 0.0f, gy = 0.0f, gz = 0.0f;
#pragma unroll
        for (int l = 12 * w; l < 12 * w + 12; l++) {
            const float wgt = fmaf(bs2f(sS[k * 49 + l]), sfk[l],
                                   bs2f(sS[l * 49 + k]) * fk);
            const f4 ul = *(const f4*)&su[4 * l];
            gx = fmaf(wgt, ul.x, gx);
            gy = fmaf(wgt, ul.y, gy);
            gz = fmaf(wgt, ul.z, gz);
        }
        sgu4[(w * 48 + k) * 3 + 0] = gx;
        sgu4[(w * 48 + k) * 3 + 1] = gy;
        sgu4[(w * 48 + k) * 3 + 2] = gz;
    }
    __syncthreads();

    // ---- phase 8d: combine partials, assemble gradient, write out ----
    if (t < K) {
        const float sgf_t = sgf4[t] + sgf4[48 + t] + sgf4[96 + t] + sgf4[144 + t];
        float gux = 0.0f, guy = 0.0f, guz = 0.0f;
#pragma unroll
        for (int ww = 0; ww < 4; ww++) {
            gux += sgu4[(ww * 48 + t) * 3 + 0];
            guy += sgu4[(ww * 48 + t) * 3 + 1];
            guz += sgu4[(ww * 48 + t) * 3 + 2];
        }
        const f4 uv = *(const f4*)&su[4 * t];
        const float d = uv.w;
        const float ux = uv.x, uy = uv.y, uz = uv.z;
        const float invd = __builtin_amdgcn_rcpf(d);
        float gfc = sgd[t * 19 + 17];
        float gdR = 0.0f;
#pragma unroll
        for (int n = 0; n < NR; n++) {
            const float bn = (float)(n + 1) * POC;
            float sn, cn;
            __sincosf(bn * d, &sn, &cn);
            const float g = sgd[t * 19 + n];
            gfc = fmaf(g, SQ * sn * invd, gfc);
            gdR = fmaf(g, SQ * (bn * cn - sn * invd) * invd, gdR);
        }
        const float fc = sfc[t];
        float dfc = 0.0f;
        if (d > RMIN_F) dfc = -0.5f * AFC * __sinf(AFC * (d - RMIN_F));
        const float dfcrik = -0.5f * POC * __sinf(POC * d);

        const float gd = fc * gdR + gfc * dfc + sgf_t * dfcrik;
        const float dot = gux * ux + guy * uy + guz * uz;

        out[base3 + 3 * t + 0] = fmaf(gd, ux, (gux - dot * ux) * invd);
        out[base3 + 3 * t + 1] = fmaf(gd, uy, (guy - dot * uy) * invd);
        out[base3 + 3 * t + 2] = fmaf(gd, uz, (guz - dot * uz) * invd);
    }
}

extern "C" void kernel_launch(void* const* d_in, const int* in_sizes, int n_in,
                              void* d_out, int out_size, void* d_ws, size_t ws_size,
                              hipStream_t stream) {
    (void)in_sizes; (void)n_in; (void)out_size; (void)d_ws; (void)ws_size;
    const float* rij = (const float*)d_in[0];
    // d_in[1] = unique_i (unused: dense K neighbors per atom)
    const float* W1 = (const float*)d_in[2];
    const float* b1 = (const float*)d_in[3];
    const float* W2 = (const float*)d_in[4];
    const float* b2 = (const float*)d_in[5];
    const float* W3 = (const float*)d_in[6];
    const float* b3 = (const float*)d_in[7];
    float* out = (float*)d_out;

    k_prep<<<48, 256, 0, stream>>>(W1, W2);
    k_fused<<<NATOMS, 256, 0, stream>>>(rij, b1, b2, W3, b3, out);
}